// Round 1
// baseline (296.048 us; speedup 1.0000x reference)
//
#include <hip/hip_runtime.h>

// SHEmbed: out[i, c] = clip( sum_j B[i,j] * sh_data[y[i], x[i], j, c], 0, 1 )
// L = 3 -> 16 basis functions, 3 channels. Closed-form real SH matching the
// reference's normalization and (-1)^m sign convention:
//   m  > 0: sqrt2 * (-1)^m * N(l,m) * P_lm(ct) * cos(m phi)
//   m  < 0: sqrt2 * (-1)^m * N(l,|m|) * P_l|m|(ct) * sin(|m| phi)  (note (-1)^m, m<0)
// with P without Condon-Shortley. In normalized coords (nx,ny,nz):
//   s*cos(phi) = nx, s*sin(phi) = ny, ct = nz.

#define SH_C0   0.28209479177387814f
#define SH_C1   0.48860251190291992f
#define SH_C2a  1.09254843059207907f   // xy / yz / xz
#define SH_C2b  0.31539156525252005f   // (3z^2-1)
#define SH_C2c  0.54627421529603959f   // (x^2-y^2)
#define SH_C3a  0.59004358992664352f   // y(3x^2-y^2), x(x^2-3y^2)
#define SH_C3b  2.89061144264055405f   // xyz
#define SH_C3c  0.45704579946446572f   // y(5z^2-1), x(5z^2-1)
#define SH_C3d  0.37317633259011546f   // z(5z^2-3)
#define SH_C3e  1.44530572132027702f   // z(x^2-y^2)

__global__ __launch_bounds__(256) void sh_embed_kernel(
    const int* __restrict__ ys, const int* __restrict__ xs,
    const float* __restrict__ dirs, const float* __restrict__ sh,
    float* __restrict__ out, int B)
{
    int i = blockIdx.x * 256 + threadIdx.x;
    if (i >= B) return;

    // Kick off the gather address early.
    int yy = ys[i];
    int xx = xs[i];
    const float4* __restrict__ c4 =
        (const float4*)(sh + (size_t)(yy * 1024 + xx) * 48u);

    float dx = dirs[3 * i + 0];
    float dy = dirs[3 * i + 1];
    float dz = dirs[3 * i + 2];
    float inv = rsqrtf(fmaf(dx, dx, fmaf(dy, dy, dz * dz)));
    float nx = dx * inv, ny = dy * inv, nz = dz * inv;

    float x2 = nx * nx, y2 = ny * ny, z2 = nz * nz;
    float xy = nx * ny, yz = ny * nz, xz = nx * nz;

    float b[16];
    b[0]  =  SH_C0;
    b[1]  = -SH_C1 * ny;
    b[2]  =  SH_C1 * nz;
    b[3]  = -SH_C1 * nx;
    b[4]  =  SH_C2a * xy;
    b[5]  = -SH_C2a * yz;
    b[6]  =  SH_C2b * (3.0f * z2 - 1.0f);
    b[7]  = -SH_C2a * xz;
    b[8]  =  SH_C2c * (x2 - y2);
    b[9]  = -SH_C3a * ny * (3.0f * x2 - y2);
    b[10] =  SH_C3b * xy * nz;
    b[11] = -SH_C3c * ny * (5.0f * z2 - 1.0f);
    b[12] =  SH_C3d * nz * (5.0f * z2 - 3.0f);
    b[13] = -SH_C3c * nx * (5.0f * z2 - 1.0f);
    b[14] =  SH_C3e * nz * (x2 - y2);
    b[15] = -SH_C3a * nx * (x2 - 3.0f * y2);

    // 12 independent float4 loads cover the 48 coefs [16 coefs x 3 channels].
    float s0 = 0.0f, s1 = 0.0f, s2 = 0.0f;
#pragma unroll
    for (int j = 0; j < 12; ++j) {
        float4 v = c4[j];
        int k = 4 * j;
        {
            int k0 = k + 0;
            float* acc = (k0 % 3 == 0) ? &s0 : (k0 % 3 == 1) ? &s1 : &s2;
            *acc = fmaf(b[k0 / 3], v.x, *acc);
        }
        {
            int k1 = k + 1;
            float* acc = (k1 % 3 == 0) ? &s0 : (k1 % 3 == 1) ? &s1 : &s2;
            *acc = fmaf(b[k1 / 3], v.y, *acc);
        }
        {
            int k2 = k + 2;
            float* acc = (k2 % 3 == 0) ? &s0 : (k2 % 3 == 1) ? &s1 : &s2;
            *acc = fmaf(b[k2 / 3], v.z, *acc);
        }
        {
            int k3 = k + 3;
            float* acc = (k3 % 3 == 0) ? &s0 : (k3 % 3 == 1) ? &s1 : &s2;
            *acc = fmaf(b[k3 / 3], v.w, *acc);
        }
    }

    out[3 * i + 0] = fminf(fmaxf(s0, 0.0f), 1.0f);
    out[3 * i + 1] = fminf(fmaxf(s1, 0.0f), 1.0f);
    out[3 * i + 2] = fminf(fmaxf(s2, 0.0f), 1.0f);
}

extern "C" void kernel_launch(void* const* d_in, const int* in_sizes, int n_in,
                              void* d_out, int out_size, void* d_ws, size_t ws_size,
                              hipStream_t stream) {
    const int*   ys   = (const int*)d_in[0];
    const int*   xs   = (const int*)d_in[1];
    const float* dirs = (const float*)d_in[2];
    const float* sh   = (const float*)d_in[3];
    float* out = (float*)d_out;
    int B = in_sizes[0];
    int blocks = (B + 255) / 256;
    sh_embed_kernel<<<blocks, 256, 0, stream>>>(ys, xs, dirs, sh, out, B);
}

// Round 2
// 287.941 us; speedup vs baseline: 1.0282x; 1.0282x over previous
//
#include <hip/hip_runtime.h>

// SHEmbed, 4-lane cooperative gather version.
// out[i,c] = clip( sum_j B[i,j] * sh_data[y[i],x[i],j,c], 0, 1 ), L=3 (16 basis, 3 ch).
// Cell = 48 floats = 192 B, 16B-aligned (192 = 12*16). Lanes 4r..4r+3 handle ray r:
// lane q loads float4 chunks q, q+4, q+8 -> wave-level loads are 4-lane coalesced
// (16 rays x 64 contiguous bytes per instruction instead of 64 divergent lines).

#define SH_C0   0.28209479177387814f
#define SH_C1   0.48860251190291992f
#define SH_C2a  1.09254843059207907f
#define SH_C2b  0.31539156525252005f
#define SH_C2c  0.54627421529603959f
#define SH_C3a  0.59004358992664352f
#define SH_C3b  2.89061144264055405f
#define SH_C3c  0.45704579946446572f
#define SH_C3d  0.37317633259011546f
#define SH_C3e  1.44530572132027702f

// chunk p covers floats 4p..4p+3 of the cell; float f -> (j=f/3, c=f%3)
#define DO4(v, J0,C0, J1,C1, J2,C2, J3,C3)        \
    s##C0 = fmaf(b[J0], (v).x, s##C0);            \
    s##C1 = fmaf(b[J1], (v).y, s##C1);            \
    s##C2 = fmaf(b[J2], (v).z, s##C2);            \
    s##C3 = fmaf(b[J3], (v).w, s##C3);

__global__ __launch_bounds__(256) void sh_embed_coop(
    const int* __restrict__ ys, const int* __restrict__ xs,
    const float* __restrict__ dirs, const float* __restrict__ sh,
    float* __restrict__ out, int B)
{
    const int tid  = blockIdx.x * 256 + threadIdx.x;
    const int ray  = tid >> 2;          // 4 lanes per ray
    const int q    = tid & 3;           // lane's chunk phase
    if (ray >= B) return;

    // Index loads (4 lanes same address -> broadcast, no extra traffic).
    const int yy = ys[ray];
    const int xx = xs[ray];
    const float4* __restrict__ c4 =
        (const float4*)(sh + (size_t)(yy * 1024 + xx) * 48u);

    // Issue the three gather loads early; compute basis while they fly.
    const float4 v0 = c4[q];
    const float4 v1 = c4[q + 4];
    const float4 v2 = c4[q + 8];

    const float dx = dirs[3 * ray + 0];
    const float dy = dirs[3 * ray + 1];
    const float dz = dirs[3 * ray + 2];
    const float inv = rsqrtf(fmaf(dx, dx, fmaf(dy, dy, dz * dz)));
    const float nx = dx * inv, ny = dy * inv, nz = dz * inv;

    const float x2 = nx * nx, y2 = ny * ny, z2 = nz * nz;
    const float xy = nx * ny, yz = ny * nz, xz = nx * nz;

    float b[16];
    b[0]  =  SH_C0;
    b[1]  = -SH_C1 * ny;
    b[2]  =  SH_C1 * nz;
    b[3]  = -SH_C1 * nx;
    b[4]  =  SH_C2a * xy;
    b[5]  = -SH_C2a * yz;
    b[6]  =  SH_C2b * (3.0f * z2 - 1.0f);
    b[7]  = -SH_C2a * xz;
    b[8]  =  SH_C2c * (x2 - y2);
    b[9]  = -SH_C3a * ny * (3.0f * x2 - y2);
    b[10] =  SH_C3b * xy * nz;
    b[11] = -SH_C3c * ny * (5.0f * z2 - 1.0f);
    b[12] =  SH_C3d * nz * (5.0f * z2 - 3.0f);
    b[13] = -SH_C3c * nx * (5.0f * z2 - 1.0f);
    b[14] =  SH_C3e * nz * (x2 - y2);
    b[15] = -SH_C3a * nx * (x2 - 3.0f * y2);

    float s0 = 0.0f, s1 = 0.0f, s2 = 0.0f;
    switch (q) {
    case 0:
        DO4(v0,  0,0,  0,1,  0,2,  1,0)
        DO4(v1,  5,1,  5,2,  6,0,  6,1)
        DO4(v2, 10,2, 11,0, 11,1, 11,2)
        break;
    case 1:
        DO4(v0,  1,1,  1,2,  2,0,  2,1)
        DO4(v1,  6,2,  7,0,  7,1,  7,2)
        DO4(v2, 12,0, 12,1, 12,2, 13,0)
        break;
    case 2:
        DO4(v0,  2,2,  3,0,  3,1,  3,2)
        DO4(v1,  8,0,  8,1,  8,2,  9,0)
        DO4(v2, 13,1, 13,2, 14,0, 14,1)
        break;
    default:
        DO4(v0,  4,0,  4,1,  4,2,  5,0)
        DO4(v1,  9,1,  9,2, 10,0, 10,1)
        DO4(v2, 14,2, 15,0, 15,1, 15,2)
        break;
    }

    // Quad butterfly reduction: all 4 lanes end with the full channel sums.
    s0 += __shfl_xor(s0, 1, 64);  s0 += __shfl_xor(s0, 2, 64);
    s1 += __shfl_xor(s1, 1, 64);  s1 += __shfl_xor(s1, 2, 64);
    s2 += __shfl_xor(s2, 1, 64);  s2 += __shfl_xor(s2, 2, 64);

    // Lane 4r+q (q<3) writes out[3*ray+q] -> coalesced 192 B per wave.
    if (q < 3) {
        float val = (q == 0) ? s0 : (q == 1) ? s1 : s2;
        out[(size_t)3 * ray + q] = fminf(fmaxf(val, 0.0f), 1.0f);
    }
}

extern "C" void kernel_launch(void* const* d_in, const int* in_sizes, int n_in,
                              void* d_out, int out_size, void* d_ws, size_t ws_size,
                              hipStream_t stream) {
    const int*   ys   = (const int*)d_in[0];
    const int*   xs   = (const int*)d_in[1];
    const float* dirs = (const float*)d_in[2];
    const float* sh   = (const float*)d_in[3];
    float* out = (float*)d_out;
    int B = in_sizes[0];
    // 4 threads per ray, 256 threads per block -> 64 rays/block.
    int blocks = (B + 63) / 64;
    sh_embed_coop<<<blocks, 256, 0, stream>>>(ys, xs, dirs, sh, out, B);
}